// Round 1
// 451.519 us; speedup vs baseline: 1.0206x; 1.0206x over previous
//
#include <hip/hip_runtime.h>
#include <hip/hip_fp16.h>

typedef _Float16 half8 __attribute__((ext_vector_type(8)));
typedef float floatx4 __attribute__((ext_vector_type(4)));

constexpr int kS = 4096;
constexpr int kD = 1024;
constexpr int kH = 16;
constexpr int kDh = 64;
constexpr int kF = 4096;
constexpr int kNQKV = kF + 3 * kD;   // 7168
constexpr int kKOut = kF + kD;       // 5120

__device__ __forceinline__ void async_ld16(const void* g, void* l) {
  __builtin_amdgcn_global_load_lds(
      (const __attribute__((address_space(1))) void*)g,
      (__attribute__((address_space(3))) void*)l, 16, 0, 0);
}

// ---------------------------------------------------------------- prep0: weight transposes (12288 blocks) + LayerNorm (4096 blocks)
__global__ __launch_bounds__(256) void prep0_kernel(
    const float* __restrict__ w_in, const float* __restrict__ wq,
    const float* __restrict__ wk, const float* __restrict__ wv,
    const float* __restrict__ w_mo, const float* __restrict__ w_ao,
    _Float16* __restrict__ Wqkv, _Float16* __restrict__ Wout,
    const float* __restrict__ x, const float* __restrict__ ln_scale,
    const float* __restrict__ ln_bias, _Float16* __restrict__ xn) {
  __shared__ float t[32][33];
  __shared__ float red[8];
  int id = blockIdx.x;
  const int tid = threadIdx.x;

  if (id >= 12288) {  // ---- LayerNorm row
    const int row = id - 12288;
    const float* xr = x + (size_t)row * kD;
    float v[4];
    float s = 0.f, sq = 0.f;
#pragma unroll
    for (int i = 0; i < 4; ++i) {
      v[i] = xr[tid + 256 * i];
      s += v[i];
      sq += v[i] * v[i];
    }
    for (int off = 32; off; off >>= 1) {
      s += __shfl_xor(s, off);
      sq += __shfl_xor(sq, off);
    }
    const int wv2 = tid >> 6;
    if ((tid & 63) == 0) { red[wv2] = s; red[wv2 + 4] = sq; }
    __syncthreads();
    s = red[0] + red[1] + red[2] + red[3];
    sq = red[4] + red[5] + red[6] + red[7];
    const float mean = s * (1.0f / kD);
    const float var = sq * (1.0f / kD) - mean * mean;
    const float rstd = rsqrtf(var + 1e-6f);
#pragma unroll
    for (int i = 0; i < 4; ++i) {
      int d = tid + 256 * i;
      xn[(size_t)row * kD + d] = (_Float16)((v[i] - mean) * rstd * ln_scale[d] + ln_bias[d]);
    }
    return;
  }

  // ---- weight transpose tile
  const float* src; _Float16* dst; int N, ldk, noff, koff, nt, kt;
  if (id < 4096)       { src = w_in; dst = Wqkv; N = kF; ldk = kD; noff = 0;        koff = 0;  nt = id & 127; kt = id >> 7; }
  else if (id < 5120)  { id -= 4096; src = wq;  dst = Wqkv; N = kD; ldk = kD; noff = kF;       koff = 0;  nt = id & 31; kt = id >> 5; }
  else if (id < 6144)  { id -= 5120; src = wk;  dst = Wqkv; N = kD; ldk = kD; noff = kF + kD;  koff = 0;  nt = id & 31; kt = id >> 5; }
  else if (id < 7168)  { id -= 6144; src = wv;  dst = Wqkv; N = kD; ldk = kD; noff = kF + 2*kD; koff = 0; nt = id & 31; kt = id >> 5; }
  else if (id < 11264) { id -= 7168; src = w_mo; dst = Wout; N = kD; ldk = kKOut; noff = 0;    koff = 0;  nt = id & 31; kt = id >> 5; }
  else                 { id -= 11264; src = w_ao; dst = Wout; N = kD; ldk = kKOut; noff = 0;   koff = kF; nt = id & 31; kt = id >> 5; }
  const int n0 = nt * 32, k0 = kt * 32;
#pragma unroll
  for (int i = 0; i < 4; ++i) {
    const int kl = (tid >> 5) + i * 8, nl = tid & 31;
    t[kl][nl] = src[(size_t)(k0 + kl) * N + n0 + nl];
  }
  __syncthreads();
#pragma unroll
  for (int i = 0; i < 4; ++i) {
    const int nl = (tid >> 5) + i * 8, kl = tid & 31;
    dst[(size_t)(noff + n0 + nl) * ldk + koff + k0 + kl] = (_Float16)t[kl][nl];
  }
}

// fp16 transpose: src [R][C] -> dst [C][R]
__global__ __launch_bounds__(256) void htrans_kernel(
    const _Float16* __restrict__ src, _Float16* __restrict__ dst, int R, int C) {
  __shared__ _Float16 t[32][34];
  const int tid = threadIdx.x;
  const int c0 = blockIdx.x * 32, r0 = blockIdx.y * 32;
#pragma unroll
  for (int i = 0; i < 4; ++i) {
    const int rl = (tid >> 5) + i * 8, cl = tid & 31;
    t[rl][cl] = src[(size_t)(r0 + rl) * C + c0 + cl];
  }
  __syncthreads();
#pragma unroll
  for (int i = 0; i < 4; ++i) {
    const int cl = (tid >> 5) + i * 8, rl = tid & 31;
    dst[(size_t)(c0 + cl) * R + r0 + rl] = t[rl][cl];
  }
}

// fast tanh-gelu
__device__ __forceinline__ float fast_gelu(float xv) {
  const float z = 0.7978845608028654f * (xv + 0.044715f * xv * xv * xv);
  const float u = exp2f(fminf(2.885390081777927f * z, 80.0f));
  return xv * u / (1.0f + u);
}

// ---------------------------------------------------------------- fused QKV+MLP-in GEMM (+fused qk-LayerNorm)
// R6: 2-phase double-buffered LDS staging. Raw s_barrier + explicit
// vmcnt(0) at END of iteration so next-tile global_load_lds stays in
// flight across the ds_read+MFMA phase (the old __syncthreads drained
// vmcnt to 0 before every MFMA phase -> ~60% stall, MfmaUtil 17%).
__global__ __launch_bounds__(256) void gemm_qkvin(
    const _Float16* __restrict__ A, const _Float16* __restrict__ Bp,
    const float* __restrict__ b_in, const float* __restrict__ bq,
    const float* __restrict__ bk, const float* __restrict__ bv,
    const float* __restrict__ qn_scale, const float* __restrict__ kn_scale,
    _Float16* __restrict__ ho, _Float16* __restrict__ q,
    _Float16* __restrict__ k, _Float16* __restrict__ v) {
  __shared__ alignas(16) _Float16 Ts[2][16 * 512];  // 32 KB double-buffered

  const int tid = threadIdx.x;
  const int lane = tid & 63;
  const int wave = tid >> 6;
  const int wm = (wave >> 1) * 64;
  const int wn = (wave & 1) * 64;
  const int m0 = blockIdx.x * 128;
  const int n0 = blockIdx.y * 128;
  const int lrow = lane & 15;
  const int quad = lane >> 4;

  floatx4 acc[4][4] = {};

  auto stage = [&](int buf, int k0) {
#pragma unroll
    for (int i = 0; i < 4; ++i) {
      const int chunk = wave * 4 + i;
      const int r = ((chunk & 7) << 4) + (lane >> 2);
      const int csrc = ((lane & 3) ^ ((r >> 1) & 3)) << 3;
      const _Float16* src = (chunk < 8)
          ? A + (size_t)(m0 + r) * kD + k0 + csrc
          : Bp + (size_t)(n0 + r) * kD + k0 + csrc;
      async_ld16(src, &Ts[buf][chunk * 512]);
    }
  };

  // prologue: fill buf0, drain, barrier
  stage(0, 0);
  asm volatile("s_waitcnt vmcnt(0)" ::: "memory");
  __builtin_amdgcn_s_barrier();

  int cur = 0;
  for (int k0 = 0; k0 < kD; k0 += 32) {
    if (k0 + 32 < kD) stage(cur ^ 1, k0 + 32);  // issue BEFORE compute

    const _Float16* As = Ts[cur];
    const _Float16* Bs = Ts[cur] + 8 * 512;
    half8 af[4], bf[4];
#pragma unroll
    for (int i = 0; i < 4; ++i) {
      const int ra = wm + i * 16 + lrow;
      const int rb = wn + i * 16 + lrow;
      af[i] = *reinterpret_cast<const half8*>(&As[ra * 32 + ((quad ^ ((ra >> 1) & 3)) << 3)]);
      bf[i] = *reinterpret_cast<const half8*>(&Bs[rb * 32 + ((quad ^ ((rb >> 1) & 3)) << 3)]);
    }
#pragma unroll
    for (int i = 0; i < 4; ++i)
#pragma unroll
      for (int j = 0; j < 4; ++j)
        acc[i][j] = __builtin_amdgcn_mfma_f32_16x16x32_f16(af[i], bf[j], acc[i][j], 0, 0, 0);

    // wait only for THIS iteration's staged loads (prev drained last iter)
    asm volatile("s_waitcnt vmcnt(0)" ::: "memory");
    __builtin_amdgcn_s_barrier();
    cur ^= 1;
  }

  const int nblk = n0 + wn;
  if (nblk < kF) {  // gelu -> ho
#pragma unroll
    for (int i = 0; i < 4; ++i) {
      const int gm = m0 + wm + i * 16 + quad * 4;
#pragma unroll
      for (int j = 0; j < 4; ++j) {
        const int gn = nblk + j * 16 + lrow;
        const float bn = b_in[gn];
#pragma unroll
        for (int r = 0; r < 4; ++r)
          ho[(size_t)(gm + r) * kKOut + gn] = (_Float16)fast_gelu(acc[i][j][r] + bn);
      }
    }
  } else if (nblk >= kF + 2 * kD) {  // v plain
#pragma unroll
    for (int i = 0; i < 4; ++i) {
      const int gm = m0 + wm + i * 16 + quad * 4;
#pragma unroll
      for (int j = 0; j < 4; ++j) {
        const int gn = nblk + j * 16 + lrow;
        const float bn = bv[(gn - kF) & (kD - 1)];
#pragma unroll
        for (int r = 0; r < 4; ++r)
          v[(size_t)(gm + r) * kD + ((gn - kF) & (kD - 1))] = (_Float16)(acc[i][j][r] + bn);
      }
    }
  } else {  // q or k: fused per-head LayerNorm (wave's 64 cols = one head)
    const bool isq = nblk < kF + kD;
    const float* nsc = isq ? qn_scale : kn_scale;
    const float* nb = isq ? bq : bk;
    const float sm = isq ? 0.18033688f : 1.0f;  // q: fold 0.125*log2e
    _Float16* dst = isq ? q : k;
    const int col0 = (nblk - kF) & (kD - 1);
    float bj[4];
#pragma unroll
    for (int j = 0; j < 4; ++j) bj[j] = nb[col0 + j * 16 + lrow];
#pragma unroll
    for (int i = 0; i < 4; ++i) {
      const int gm = m0 + wm + i * 16 + quad * 4;
#pragma unroll
      for (int r = 0; r < 4; ++r) {
        float vals[4], s1 = 0.f, s2 = 0.f;
#pragma unroll
        for (int j = 0; j < 4; ++j) {
          const float vv = acc[i][j][r] + bj[j];
          vals[j] = vv; s1 += vv; s2 += vv * vv;
        }
#pragma unroll
        for (int off = 1; off <= 8; off <<= 1) {
          s1 += __shfl_xor(s1, off);
          s2 += __shfl_xor(s2, off);
        }
        const float mean = s1 * (1.0f / 64.0f);
        const float rstd = rsqrtf(s2 * (1.0f / 64.0f) - mean * mean + 1e-6f);
#pragma unroll
        for (int j = 0; j < 4; ++j) {
          const int d = j * 16 + lrow;
          dst[(size_t)(gm + r) * kD + col0 + d] =
              (_Float16)((vals[j] - mean) * rstd * nsc[d] * sm);
        }
      }
    }
  }
}

// ---------------------------------------------------------------- prep: out = x + b_mo + b_ao ; zero Oacc/Lacc
__global__ __launch_bounds__(256) void prep_kernel(
    const float* __restrict__ x, const float* __restrict__ b_mo,
    const float* __restrict__ b_ao, float* __restrict__ out,
    float* __restrict__ Oacc, float* __restrict__ Lacc) {
  const int i = blockIdx.x * 256 + threadIdx.x;
  if (i < kS * kD) {
    const int d = i & (kD - 1);
    out[i] = x[i] + b_mo[d] + b_ao[d];
    Oacc[i] = 0.f;
  } else if (i < kS * kD + kS * kH) {
    Lacc[i - kS * kD] = 0.f;
  }
}

// ---------------------------------------------------------------- fused out GEMM, 128x128, split-K=2, atomic accumulate
// R6: same 2-phase double-buffer conversion as gemm_qkvin.
__global__ __launch_bounds__(256) void gemm_out(
    const _Float16* __restrict__ A, const _Float16* __restrict__ Bp,
    float* __restrict__ out) {
  __shared__ alignas(16) _Float16 Ts[2][16 * 512];  // 32 KB double-buffered

  const int tid = threadIdx.x;
  const int lane = tid & 63;
  const int wave = tid >> 6;
  const int wm = (wave >> 1) * 64;
  const int wn = (wave & 1) * 64;
  const int m0 = blockIdx.x * 128;
  const int n0 = blockIdx.y * 128;
  const int kbeg = blockIdx.z * (kKOut / 2);
  const int kend = kbeg + kKOut / 2;
  const int lrow = lane & 15;
  const int quad = lane >> 4;

  floatx4 acc[4][4] = {};

  auto stage = [&](int buf, int k0) {
#pragma unroll
    for (int i = 0; i < 4; ++i) {
      const int chunk = wave * 4 + i;
      const int r = ((chunk & 7) << 4) + (lane >> 2);
      const int csrc = ((lane & 3) ^ ((r >> 1) & 3)) << 3;
      const _Float16* src = (chunk < 8)
          ? A + (size_t)(m0 + r) * kKOut + k0 + csrc
          : Bp + (size_t)(n0 + r) * kKOut + k0 + csrc;
      async_ld16(src, &Ts[buf][chunk * 512]);
    }
  };

  stage(0, kbeg);
  asm volatile("s_waitcnt vmcnt(0)" ::: "memory");
  __builtin_amdgcn_s_barrier();

  int cur = 0;
  for (int k0 = kbeg; k0 < kend; k0 += 32) {
    if (k0 + 32 < kend) stage(cur ^ 1, k0 + 32);

    const _Float16* As = Ts[cur];
    const _Float16* Bs = Ts[cur] + 8 * 512;
    half8 af[4], bf[4];
#pragma unroll
    for (int i = 0; i < 4; ++i) {
      const int ra = wm + i * 16 + lrow;
      const int rb = wn + i * 16 + lrow;
      af[i] = *reinterpret_cast<const half8*>(&As[ra * 32 + ((quad ^ ((ra >> 1) & 3)) << 3)]);
      bf[i] = *reinterpret_cast<const half8*>(&Bs[rb * 32 + ((quad ^ ((rb >> 1) & 3)) << 3)]);
    }
#pragma unroll
    for (int i = 0; i < 4; ++i)
#pragma unroll
      for (int j = 0; j < 4; ++j)
        acc[i][j] = __builtin_amdgcn_mfma_f32_16x16x32_f16(af[i], bf[j], acc[i][j], 0, 0, 0);

    asm volatile("s_waitcnt vmcnt(0)" ::: "memory");
    __builtin_amdgcn_s_barrier();
    cur ^= 1;
  }

#pragma unroll
  for (int i = 0; i < 4; ++i) {
    const int gm = m0 + wm + i * 16 + quad * 4;
#pragma unroll
    for (int j = 0; j < 4; ++j) {
      const int gn = n0 + wn + j * 16 + lrow;
#pragma unroll
      for (int r = 0; r < 4; ++r)
        atomicAdd(out + (size_t)(gm + r) * kD + gn, acc[i][j][r]);
    }
  }
}

// ---------------------------------------------------------------- flash attention (R5 config: measured-best 102 us)
// grid (32, 16, 2): pair of 64-row q-tiles {p,63-p} x head x 2 k-splits.
// P through LDS (stride 72), 16x16x32 PV. No-max softmax (|s|<=8 after
// qk-LN; 0.125*log2e folded into q), per-lane l, additive combine via atomics.
__global__ __launch_bounds__(256) void fattn_kernel(
    const _Float16* __restrict__ Q, const _Float16* __restrict__ K,
    const _Float16* __restrict__ Vt, float* __restrict__ Oacc,
    float* __restrict__ Lacc) {
  __shared__ alignas(16) _Float16 Qs[64 * 64];   // 8 KB swizzled (chunk ^ (r&7))
  __shared__ alignas(16) _Float16 Ks[64 * 64];   // 8 KB rows=key
  __shared__ alignas(16) _Float16 Vs[64 * 64];   // 8 KB rows=dh
  __shared__ alignas(16) _Float16 Ps[64 * 72];   // 9 KB padded

  const int tid = threadIdx.x;
  const int lane = tid & 63;
  const int wave = tid >> 6;
  const int lrow = lane & 15;
  const int quad = lane >> 4;
  const int h = blockIdx.y;
  const int pair = blockIdx.x;
  const int split = blockIdx.z;

  const int rs = lane >> 3;
  const int cs = lane & 7;
  constexpr float kOff = 11.5415603f;  // 8*log2(e)

  for (int pass = 0; pass < 2; ++pass) {
    const int qtile = pass ? (63 - pair) : pair;
    const int qbase = qtile * 64;

    __syncthreads();
#pragma unroll
    for (int i = 0; i < 2; ++i) {  // Q: 8 chunks x 8 rows
      const int chunk = wave * 2 + i;
      const int r = chunk * 8 + rs;
      async_ld16(Q + (size_t)(qbase + r) * kD + h * kDh + ((cs ^ (r & 7)) << 3),
                 Qs + chunk * 512);
    }
    __syncthreads();

    half8 qf[2];
#pragma unroll
    for (int kt = 0; kt < 2; ++kt) {
      const int row = wave * 16 + lrow;
      qf[kt] = *reinterpret_cast<const half8*>(
          &Qs[row * 64 + (((kt * 4 + quad) ^ (row & 7)) << 3)]);
    }

    float lst[4] = {0.f, 0.f, 0.f, 0.f};
    floatx4 oacc[4] = {};
    const int qw = qbase + wave * 16;

    for (int t = split; t <= qtile; t += 2) {
      const int k0 = t * 64;
      __syncthreads();
#pragma unroll
      for (int i = 0; i < 4; ++i) {
        const int c2 = wave * 4 + i;
        if (c2 < 8) {
          const int r = c2 * 8 + rs;
          async_ld16(K + (size_t)(k0 + r) * kD + h * kDh + ((cs ^ (r & 7)) << 3),
                     Ks + c2 * 512);
        } else {
          const int c = c2 - 8;
          const int r = c * 8 + rs;
          async_ld16(Vt + (size_t)(h * kDh + r) * kS + k0 + ((cs ^ (r & 7)) << 3),
                     Vs + c * 512);
        }
      }
      __syncthreads();

      const bool diag = (t == qtile);

      floatx4 sacc[4] = {};
#pragma unroll
      for (int jt = 0; jt < 4; ++jt) {
        if (diag && jt > wave) continue;  // fully-masked key block
#pragma unroll
        for (int kt = 0; kt < 2; ++kt) {
          const int rb = jt * 16 + lrow;
          half8 bfk = *reinterpret_cast<const half8*>(
              &Ks[rb * 64 + (((kt * 4 + quad) ^ (rb & 7)) << 3)]);
          sacc[jt] = __builtin_amdgcn_mfma_f32_16x16x32_f16(qf[kt], bfk, sacc[jt], 0, 0, 0);
        }
      }

      if (diag) {
#pragma unroll
        for (int jt = 0; jt < 4; ++jt) {
          const int kg = k0 + jt * 16 + lrow;
#pragma unroll
          for (int r = 0; r < 4; ++r)
            if (kg > qw + quad * 4 + r) sacc[jt][r] = -1e30f;
        }
      }

#pragma unroll
      for (int jt = 0; jt < 4; ++jt)
#pragma unroll
        for (int r = 0; r < 4; ++r) {
          const float p = exp2f(sacc[jt][r] - kOff);
          sacc[jt][r] = p;
          lst[r] += p;
        }

#pragma unroll
      for (int jt = 0; jt < 4; ++jt)
#pragma unroll
        for (int r = 0; r < 4; ++r)
          Ps[(wave * 16 + quad * 4 + r) * 72 + jt * 16 + lrow] = (_Float16)sacc[jt][r];

      const int ktmax = (diag && wave < 2) ? 1 : 2;
      for (int kt = 0; kt < ktmax; ++kt) {
        half8 pf = *reinterpret_cast<const half8*>(
            &Ps[(wave * 16 + lrow) * 72 + (kt * 4 + quad) * 8]);
#pragma unroll
        for (int jt = 0; jt < 4; ++jt) {
          const int rb = jt * 16 + lrow;
          half8 vf = *reinterpret_cast<const half8*>(
              &Vs[rb * 64 + (((kt * 4 + quad) ^ (rb & 7)) << 3)]);
          oacc[jt] = __builtin_amdgcn_mfma_f32_16x16x32_f16(pf, vf, oacc[jt], 0, 0, 0);
        }
      }
    }

    // epilogue: reduce l over 16 cols, accumulate partials
#pragma unroll
    for (int r = 0; r < 4; ++r)
#pragma unroll
      for (int off = 8; off; off >>= 1) lst[r] += __shfl_xor(lst[r], off);
#pragma unroll
    for (int r = 0; r < 4; ++r) {
      const int qg = qw + quad * 4 + r;
      if (lrow == 0) atomicAdd(Lacc + qg * kH + h, lst[r]);
#pragma unroll
      for (int jt = 0; jt < 4; ++jt)
        atomicAdd(Oacc + ((size_t)qg * kH + h) * kDh + jt * 16 + lrow, oacc[jt][r]);
    }
  }
}

// ---------------------------------------------------------------- normalize: ho attn columns = Oacc / Lacc
__global__ __launch_bounds__(256) void norm_kernel(
    const float* __restrict__ Oacc, const float* __restrict__ Lacc,
    _Float16* __restrict__ ho) {
  const int idx = blockIdx.x * 256 + threadIdx.x;
  const int q = idx >> 10, rem = idx & 1023;
  const float l = Lacc[(q << 4) + (rem >> 6)];
  ho[(size_t)q * kKOut + kF + rem] = (_Float16)(Oacc[idx] / l);
}

// ---------------------------------------------------------------- launch
extern "C" void kernel_launch(void* const* d_in, const int* in_sizes, int n_in,
                              void* d_out, int out_size, void* d_ws, size_t ws_size,
                              hipStream_t stream) {
  const float* x        = (const float*)d_in[0];
  const float* ln_scale = (const float*)d_in[2];
  const float* ln_bias  = (const float*)d_in[3];
  const float* w_in     = (const float*)d_in[4];
  const float* b_in     = (const float*)d_in[5];
  const float* wq       = (const float*)d_in[6];
  const float* bq       = (const float*)d_in[7];
  const float* wk       = (const float*)d_in[8];
  const float* bk       = (const float*)d_in[9];
  const float* wv       = (const float*)d_in[10];
  const float* bv       = (const float*)d_in[11];
  const float* qn_scale = (const float*)d_in[12];
  const float* kn_scale = (const float*)d_in[13];
  const float* w_mo     = (const float*)d_in[14];
  const float* b_mo     = (const float*)d_in[15];
  const float* w_ao     = (const float*)d_in[16];
  const float* b_ao     = (const float*)d_in[17];
  float* out = (float*)d_out;

  char* ws = (char*)d_ws;
  size_t off = 0;
  auto alloc = [&](size_t bytes) { char* p = ws + off; off += bytes; return p; };
  // alias zone: xn+Wqkv dead after gemm_qkvin; Oacc/Lacc overlay
  char* zone = (char*)alloc((size_t)kS * kD * 2 + (size_t)kNQKV * kD * 2);
  _Float16* xn   = (_Float16*)zone;
  _Float16* Wqkv = (_Float16*)(zone + (size_t)kS * kD * 2);
  float* Oacc = (float*)zone;
  float* Lacc = (float*)(zone + (size_t)kS * kD * 4);
  _Float16* Wout = (_Float16*)alloc((size_t)kD * kKOut * 2);
  _Float16* ho   = (_Float16*)alloc((size_t)kS * kKOut * 2);
  _Float16* q_h  = (_Float16*)alloc((size_t)kS * kD * 2);
  _Float16* k_h  = (_Float16*)alloc((size_t)kS * kD * 2);
  _Float16* v_h  = (_Float16*)alloc((size_t)kS * kD * 2);
  _Float16* v_t  = (_Float16*)alloc((size_t)kS * kD * 2);

  prep0_kernel<<<12288 + 4096, 256, 0, stream>>>(
      w_in, wq, wk, wv, w_mo, w_ao, Wqkv, Wout, x, ln_scale, ln_bias, xn);

  gemm_qkvin<<<dim3(kS / 128, kNQKV / 128), 256, 0, stream>>>(
      xn, Wqkv, b_in, bq, bk, bv, qn_scale, kn_scale, ho, q_h, k_h, v_h);

  htrans_kernel<<<dim3(kD / 32, kS / 32), 256, 0, stream>>>(v_h, v_t, kS, kD);

  prep_kernel<<<(kS * kD + kS * kH + 255) / 256, 256, 0, stream>>>(
      x, b_mo, b_ao, out, Oacc, Lacc);

  fattn_kernel<<<dim3(32, kH, 2), 256, 0, stream>>>(q_h, k_h, v_t, Oacc, Lacc);

  norm_kernel<<<kS * kD / 256, 256, 0, stream>>>(Oacc, Lacc, ho);

  gemm_out<<<dim3(kS / 128, kD / 128, 2), 256, 0, stream>>>(ho, Wout, out);
}

// Round 2
// 432.774 us; speedup vs baseline: 1.0648x; 1.0433x over previous
//
#include <hip/hip_runtime.h>
#include <hip/hip_fp16.h>

typedef _Float16 half8 __attribute__((ext_vector_type(8)));
typedef float floatx4 __attribute__((ext_vector_type(4)));

constexpr int kS = 4096;
constexpr int kD = 1024;
constexpr int kH = 16;
constexpr int kDh = 64;
constexpr int kF = 4096;
constexpr int kNQKV = kF + 3 * kD;   // 7168
constexpr int kKOut = kF + kD;       // 5120

__device__ __forceinline__ void async_ld16(const void* g, void* l) {
  __builtin_amdgcn_global_load_lds(
      (const __attribute__((address_space(1))) void*)g,
      (__attribute__((address_space(3))) void*)l, 16, 0, 0);
}

#define CFENCE() asm volatile("" ::: "memory")

// ---------------------------------------------------------------- prep0: weight transposes (12288 blocks) + LayerNorm (4096 blocks)
__global__ __launch_bounds__(256) void prep0_kernel(
    const float* __restrict__ w_in, const float* __restrict__ wq,
    const float* __restrict__ wk, const float* __restrict__ wv,
    const float* __restrict__ w_mo, const float* __restrict__ w_ao,
    _Float16* __restrict__ Wqkv, _Float16* __restrict__ Wout,
    const float* __restrict__ x, const float* __restrict__ ln_scale,
    const float* __restrict__ ln_bias, _Float16* __restrict__ xn) {
  __shared__ float t[32][33];
  __shared__ float red[8];
  int id = blockIdx.x;
  const int tid = threadIdx.x;

  if (id >= 12288) {  // ---- LayerNorm row
    const int row = id - 12288;
    const float* xr = x + (size_t)row * kD;
    float v[4];
    float s = 0.f, sq = 0.f;
#pragma unroll
    for (int i = 0; i < 4; ++i) {
      v[i] = xr[tid + 256 * i];
      s += v[i];
      sq += v[i] * v[i];
    }
    for (int off = 32; off; off >>= 1) {
      s += __shfl_xor(s, off);
      sq += __shfl_xor(sq, off);
    }
    const int wv2 = tid >> 6;
    if ((tid & 63) == 0) { red[wv2] = s; red[wv2 + 4] = sq; }
    __syncthreads();
    s = red[0] + red[1] + red[2] + red[3];
    sq = red[4] + red[5] + red[6] + red[7];
    const float mean = s * (1.0f / kD);
    const float var = sq * (1.0f / kD) - mean * mean;
    const float rstd = rsqrtf(var + 1e-6f);
#pragma unroll
    for (int i = 0; i < 4; ++i) {
      int d = tid + 256 * i;
      xn[(size_t)row * kD + d] = (_Float16)((v[i] - mean) * rstd * ln_scale[d] + ln_bias[d]);
    }
    return;
  }

  // ---- weight transpose tile
  const float* src; _Float16* dst; int N, ldk, noff, koff, nt, kt;
  if (id < 4096)       { src = w_in; dst = Wqkv; N = kF; ldk = kD; noff = 0;        koff = 0;  nt = id & 127; kt = id >> 7; }
  else if (id < 5120)  { id -= 4096; src = wq;  dst = Wqkv; N = kD; ldk = kD; noff = kF;       koff = 0;  nt = id & 31; kt = id >> 5; }
  else if (id < 6144)  { id -= 5120; src = wk;  dst = Wqkv; N = kD; ldk = kD; noff = kF + kD;  koff = 0;  nt = id & 31; kt = id >> 5; }
  else if (id < 7168)  { id -= 6144; src = wv;  dst = Wqkv; N = kD; ldk = kD; noff = kF + 2*kD; koff = 0; nt = id & 31; kt = id >> 5; }
  else if (id < 11264) { id -= 7168; src = w_mo; dst = Wout; N = kD; ldk = kKOut; noff = 0;    koff = 0;  nt = id & 31; kt = id >> 5; }
  else                 { id -= 11264; src = w_ao; dst = Wout; N = kD; ldk = kKOut; noff = 0;   koff = kF; nt = id & 31; kt = id >> 5; }
  const int n0 = nt * 32, k0 = kt * 32;
#pragma unroll
  for (int i = 0; i < 4; ++i) {
    const int kl = (tid >> 5) + i * 8, nl = tid & 31;
    t[kl][nl] = src[(size_t)(k0 + kl) * N + n0 + nl];
  }
  __syncthreads();
#pragma unroll
  for (int i = 0; i < 4; ++i) {
    const int nl = (tid >> 5) + i * 8, kl = tid & 31;
    dst[(size_t)(noff + n0 + nl) * ldk + koff + k0 + kl] = (_Float16)t[kl][nl];
  }
}

// fp16 transpose: src [R][C] -> dst [C][R]
__global__ __launch_bounds__(256) void htrans_kernel(
    const _Float16* __restrict__ src, _Float16* __restrict__ dst, int R, int C) {
  __shared__ _Float16 t[32][34];
  const int tid = threadIdx.x;
  const int c0 = blockIdx.x * 32, r0 = blockIdx.y * 32;
#pragma unroll
  for (int i = 0; i < 4; ++i) {
    const int rl = (tid >> 5) + i * 8, cl = tid & 31;
    t[rl][cl] = src[(size_t)(r0 + rl) * C + c0 + cl];
  }
  __syncthreads();
#pragma unroll
  for (int i = 0; i < 4; ++i) {
    const int cl = (tid >> 5) + i * 8, rl = tid & 31;
    dst[(size_t)(c0 + cl) * R + r0 + rl] = t[rl][cl];
  }
}

// fast tanh-gelu
__device__ __forceinline__ float fast_gelu(float xv) {
  const float z = 0.7978845608028654f * (xv + 0.044715f * xv * xv * xv);
  const float u = exp2f(fminf(2.885390081777927f * z, 80.0f));
  return xv * u / (1.0f + u);
}

// ---------------------------------------------------------------- fused QKV+MLP-in GEMM (+fused qk-LayerNorm)
// R7: 256x256 tile, BK=64, 8 waves (2M x 4N), 128 KiB LDS double-buffer,
// 4 phases per K-tile with counted vmcnt(4) (template T3+T4), XOR chunk
// swizzle c ^= row&3 on [256][32] k-half LDS layout (T2, staged via
// pre-swizzled global source), setprio around MFMA clusters (T5),
// bijective XCD block swizzle (T1).
// Phase p: ks=p>>1, N-frag pair p&1. Unit staged at phase p of tile t =
// unit p of tile t+1 (A-k0, B-k0, A-k1, B-k1). Ledger: wait vmcnt(4) at
// end of p1 (validates this tile's k1 units) and p3 (validates next
// tile's k0 units); never drained to 0 except final tile.
__global__ __launch_bounds__(512, 2) void gemm_qkvin(
    const _Float16* __restrict__ A, const _Float16* __restrict__ Bp,
    const float* __restrict__ b_in, const float* __restrict__ bq,
    const float* __restrict__ bk, const float* __restrict__ bv,
    const float* __restrict__ qn_scale, const float* __restrict__ kn_scale,
    _Float16* __restrict__ ho, _Float16* __restrict__ q,
    _Float16* __restrict__ k, _Float16* __restrict__ v) {
  // halves: [buf][mat][ks][row 256][32], 2*2*2*256*32 = 65536 halves = 128 KiB
  __shared__ alignas(16) _Float16 Ts[65536];

  const int tid = threadIdx.x;
  const int lane = tid & 63;
  const int wave = tid >> 6;
  const int wr = wave >> 2;        // 0..1  (M half)
  const int wc = wave & 3;         // 0..3  (N quarter)
  const int lrow = lane & 15;
  const int quad = lane >> 4;

  // bijective XCD swizzle (448 blocks, 448 % 8 == 0)
  int bid = blockIdx.y * 16 + blockIdx.x;
  bid = (bid & 7) * 56 + (bid >> 3);
  const int m0 = (bid & 15) * 256;
  const int n0 = (bid >> 4) * 256;

  // fragment read offsets (in halves); chunk swizzle c ^= row&3
  const int swz = ((quad ^ (lrow & 3)) << 3);
  const int aoff = (wr * 128 + lrow) * 32 + swz;          // + mi*512 + ks*8192 + cur*32768
  const int boff = 16384 + (wc * 64 + lrow) * 32 + swz;   // + nf*512 + ks*8192 + cur*32768

  // staging: per wave 2 loads/unit; lane -> (row, pre-swizzled k-chunk)
  const int srow = wave * 32 + (lane >> 2);               // i=0 rows; i=1 adds 16
  const int scol = (((lane & 3) ^ ((lane >> 2) & 3)) << 3);
  const int sldsl = wave * 1024;                          // halves; i=1 adds 512

  floatx4 acc[8][4] = {};

  auto stage = [&](int nb, int p, int kb) {  // kb = global k base of unit
    const int mat = p & 1;
    const int lds0 = nb * 32768 + mat * 16384 + (p >> 1) * 8192 + sldsl;
    const _Float16* g0 = (mat == 0)
        ? A + (size_t)(m0 + srow) * kD + kb + scol
        : Bp + (size_t)(n0 + srow) * kD + kb + scol;
    async_ld16(g0, Ts + lds0);
    async_ld16(g0 + (size_t)16 * kD, Ts + lds0 + 512);
  };

  // prologue: tile 0 fully staged; validate k0 units, keep k1 in flight
  stage(0, 0, 0);
  stage(0, 1, 0);
  stage(0, 2, 32);
  stage(0, 3, 32);
  asm volatile("s_waitcnt vmcnt(4)" ::: "memory");
  CFENCE(); __builtin_amdgcn_s_barrier(); CFENCE();

  half8 af[8];
  constexpr int NT = kD / 64;  // 16
  for (int t = 0; t < NT; ++t) {
    const int cur = t & 1, nb = cur ^ 1;
    const int co = cur * 32768;
    const bool pf = (t + 1 < NT);
    const int kb1 = (t + 1) * 64;

    auto rdA = [&](int ks) {
#pragma unroll
      for (int mi = 0; mi < 8; ++mi)
        af[mi] = *reinterpret_cast<const half8*>(Ts + co + ks * 8192 + aoff + mi * 512);
    };
    auto rdB = [&](int ks, int nf) -> half8 {
      return *reinterpret_cast<const half8*>(Ts + co + ks * 8192 + boff + nf * 512);
    };
    half8 bf0, bf1;

    auto mm2 = [&](int nf0, half8 b0, half8 b1) {
      __builtin_amdgcn_s_setprio(1);
#pragma unroll
      for (int mi = 0; mi < 8; ++mi)
        acc[mi][nf0] = __builtin_amdgcn_mfma_f32_16x16x32_f16(af[mi], b0, acc[mi][nf0], 0, 0, 0);
#pragma unroll
      for (int mi = 0; mi < 8; ++mi)
        acc[mi][nf0 + 1] = __builtin_amdgcn_mfma_f32_16x16x32_f16(af[mi], b1, acc[mi][nf0 + 1], 0, 0, 0);
      __builtin_amdgcn_s_setprio(0);
    };

    // ---- phase 0: ks=0, N-frags {0,1}
    rdA(0); bf0 = rdB(0, 0); bf1 = rdB(0, 1);
    if (pf) stage(nb, 0, kb1);
    CFENCE(); __builtin_amdgcn_s_barrier(); CFENCE();
    mm2(0, bf0, bf1);
    CFENCE(); __builtin_amdgcn_s_barrier(); CFENCE();

    // ---- phase 1: ks=0, N-frags {2,3}; validate this tile's k1 units
    bf0 = rdB(0, 2); bf1 = rdB(0, 3);
    if (pf) {
      stage(nb, 1, kb1);
      asm volatile("s_waitcnt vmcnt(4)" ::: "memory");
    } else {
      asm volatile("s_waitcnt vmcnt(0)" ::: "memory");
    }
    CFENCE(); __builtin_amdgcn_s_barrier(); CFENCE();
    mm2(2, bf0, bf1);
    CFENCE(); __builtin_amdgcn_s_barrier(); CFENCE();

    // ---- phase 2: ks=1, N-frags {0,1}
    rdA(1); bf0 = rdB(1, 0); bf1 = rdB(1, 1);
    if (pf) stage(nb, 2, kb1 + 32);
    CFENCE(); __builtin_amdgcn_s_barrier(); CFENCE();
    mm2(0, bf0, bf1);
    CFENCE(); __builtin_amdgcn_s_barrier(); CFENCE();

    // ---- phase 3: ks=1, N-frags {2,3}; validate next tile's k0 units
    bf0 = rdB(1, 2); bf1 = rdB(1, 3);
    if (pf) {
      stage(nb, 3, kb1 + 32);
      asm volatile("s_waitcnt vmcnt(4)" ::: "memory");
    }
    CFENCE(); __builtin_amdgcn_s_barrier(); CFENCE();
    mm2(2, bf0, bf1);
    CFENCE(); __builtin_amdgcn_s_barrier(); CFENCE();
  }

  // ---------------- epilogue (regions are block-uniform: boundaries at 1024-multiples)
  const int nblk0 = n0 + wc * 64;
  const int rbase = m0 + wr * 128 + quad * 4;

  if (nblk0 < kF) {  // gelu -> ho
#pragma unroll
    for (int mi = 0; mi < 8; ++mi) {
      const int gm = rbase + mi * 16;
#pragma unroll
      for (int nf = 0; nf < 4; ++nf) {
        const int gn = nblk0 + nf * 16 + lrow;
        const float bn = b_in[gn];
#pragma unroll
        for (int r = 0; r < 4; ++r)
          ho[(size_t)(gm + r) * kKOut + gn] = (_Float16)fast_gelu(acc[mi][nf][r] + bn);
      }
    }
  } else if (nblk0 >= kF + 2 * kD) {  // v plain
    const int cb = nblk0 - (kF + 2 * kD);
#pragma unroll
    for (int mi = 0; mi < 8; ++mi) {
      const int gm = rbase + mi * 16;
#pragma unroll
      for (int nf = 0; nf < 4; ++nf) {
        const int col = cb + nf * 16 + lrow;
        const float bn = bv[col];
#pragma unroll
        for (int r = 0; r < 4; ++r)
          v[(size_t)(gm + r) * kD + col] = (_Float16)(acc[mi][nf][r] + bn);
      }
    }
  } else {  // q or k: fused per-head LayerNorm (wave's 64 cols = one head)
    const bool isq = nblk0 < kF + kD;
    const float* nsc = isq ? qn_scale : kn_scale;
    const float* nb2 = isq ? bq : bk;
    const float sm = isq ? 0.18033688f : 1.0f;  // q: fold 0.125*log2e
    _Float16* dst = isq ? q : k;
    const int col0 = (nblk0 - kF) & (kD - 1);
    float bj[4];
#pragma unroll
    for (int nf = 0; nf < 4; ++nf) bj[nf] = nb2[col0 + nf * 16 + lrow];
#pragma unroll
    for (int mi = 0; mi < 8; ++mi) {
      const int gm = rbase + mi * 16;
#pragma unroll
      for (int r = 0; r < 4; ++r) {
        float vals[4], s1 = 0.f, s2 = 0.f;
#pragma unroll
        for (int nf = 0; nf < 4; ++nf) {
          const float vv = acc[mi][nf][r] + bj[nf];
          vals[nf] = vv; s1 += vv; s2 += vv * vv;
        }
#pragma unroll
        for (int off = 1; off <= 8; off <<= 1) {
          s1 += __shfl_xor(s1, off);
          s2 += __shfl_xor(s2, off);
        }
        const float mean = s1 * (1.0f / 64.0f);
        const float rstd = rsqrtf(s2 * (1.0f / 64.0f) - mean * mean + 1e-6f);
#pragma unroll
        for (int nf = 0; nf < 4; ++nf) {
          const int d = nf * 16 + lrow;
          dst[(size_t)(gm + r) * kD + col0 + d] =
              (_Float16)((vals[nf] - mean) * rstd * nsc[d] * sm);
        }
      }
    }
  }
}

// ---------------------------------------------------------------- prep: out = x + b_mo + b_ao ; zero Oacc/Lacc
__global__ __launch_bounds__(256) void prep_kernel(
    const float* __restrict__ x, const float* __restrict__ b_mo,
    const float* __restrict__ b_ao, float* __restrict__ out,
    float* __restrict__ Oacc, float* __restrict__ Lacc) {
  const int i = blockIdx.x * 256 + threadIdx.x;
  if (i < kS * kD) {
    const int d = i & (kD - 1);
    out[i] = x[i] + b_mo[d] + b_ao[d];
    Oacc[i] = 0.f;
  } else if (i < kS * kD + kS * kH) {
    Lacc[i - kS * kD] = 0.f;
  }
}

// ---------------------------------------------------------------- fused out GEMM, 128x128, split-K=2, atomic accumulate
// R6: 2-phase double-buffer (unchanged this round).
__global__ __launch_bounds__(256) void gemm_out(
    const _Float16* __restrict__ A, const _Float16* __restrict__ Bp,
    float* __restrict__ out) {
  __shared__ alignas(16) _Float16 Ts[2][16 * 512];  // 32 KB double-buffered

  const int tid = threadIdx.x;
  const int lane = tid & 63;
  const int wave = tid >> 6;
  const int wm = (wave >> 1) * 64;
  const int wn = (wave & 1) * 64;
  const int m0 = blockIdx.x * 128;
  const int n0 = blockIdx.y * 128;
  const int kbeg = blockIdx.z * (kKOut / 2);
  const int kend = kbeg + kKOut / 2;
  const int lrow = lane & 15;
  const int quad = lane >> 4;

  floatx4 acc[4][4] = {};

  auto stage = [&](int buf, int k0) {
#pragma unroll
    for (int i = 0; i < 4; ++i) {
      const int chunk = wave * 4 + i;
      const int r = ((chunk & 7) << 4) + (lane >> 2);
      const int csrc = ((lane & 3) ^ ((r >> 1) & 3)) << 3;
      const _Float16* src = (chunk < 8)
          ? A + (size_t)(m0 + r) * kKOut + k0 + csrc
          : Bp + (size_t)(n0 + r) * kKOut + k0 + csrc;
      async_ld16(src, &Ts[buf][chunk * 512]);
    }
  };

  stage(0, kbeg);
  asm volatile("s_waitcnt vmcnt(0)" ::: "memory");
  __builtin_amdgcn_s_barrier();

  int cur = 0;
  for (int k0 = kbeg; k0 < kend; k0 += 32) {
    if (k0 + 32 < kend) stage(cur ^ 1, k0 + 32);

    const _Float16* As = Ts[cur];
    const _Float16* Bs = Ts[cur] + 8 * 512;
    half8 af[4], bf[4];
#pragma unroll
    for (int i = 0; i < 4; ++i) {
      const int ra = wm + i * 16 + lrow;
      const int rb = wn + i * 16 + lrow;
      af[i] = *reinterpret_cast<const half8*>(&As[ra * 32 + ((quad ^ ((ra >> 1) & 3)) << 3)]);
      bf[i] = *reinterpret_cast<const half8*>(&Bs[rb * 32 + ((quad ^ ((rb >> 1) & 3)) << 3)]);
    }
#pragma unroll
    for (int i = 0; i < 4; ++i)
#pragma unroll
      for (int j = 0; j < 4; ++j)
        acc[i][j] = __builtin_amdgcn_mfma_f32_16x16x32_f16(af[i], bf[j], acc[i][j], 0, 0, 0);

    asm volatile("s_waitcnt vmcnt(0)" ::: "memory");
    __builtin_amdgcn_s_barrier();
    cur ^= 1;
  }

#pragma unroll
  for (int i = 0; i < 4; ++i) {
    const int gm = m0 + wm + i * 16 + quad * 4;
#pragma unroll
    for (int j = 0; j < 4; ++j) {
      const int gn = n0 + wn + j * 16 + lrow;
#pragma unroll
      for (int r = 0; r < 4; ++r)
        atomicAdd(out + (size_t)(gm + r) * kD + gn, acc[i][j][r]);
    }
  }
}

// ---------------------------------------------------------------- flash attention (R5 config: measured-best 102 us)
// grid (32, 16, 2): pair of 64-row q-tiles {p,63-p} x head x 2 k-splits.
// P through LDS (stride 72), 16x16x32 PV. No-max softmax (|s|<=8 after
// qk-LN; 0.125*log2e folded into q), per-lane l, additive combine via atomics.
__global__ __launch_bounds__(256) void fattn_kernel(
    const _Float16* __restrict__ Q, const _Float16* __restrict__ K,
    const _Float16* __restrict__ Vt, float* __restrict__ Oacc,
    float* __restrict__ Lacc) {
  __shared__ alignas(16) _Float16 Qs[64 * 64];   // 8 KB swizzled (chunk ^ (r&7))
  __shared__ alignas(16) _Float16 Ks[64 * 64];   // 8 KB rows=key
  __shared__ alignas(16) _Float16 Vs[64 * 64];   // 8 KB rows=dh
  __shared__ alignas(16) _Float16 Ps[64 * 72];   // 9 KB padded

  const int tid = threadIdx.x;
  const int lane = tid & 63;
  const int wave = tid >> 6;
  const int lrow = lane & 15;
  const int quad = lane >> 4;
  const int h = blockIdx.y;
  const int pair = blockIdx.x;
  const int split = blockIdx.z;

  const int rs = lane >> 3;
  const int cs = lane & 7;
  constexpr float kOff = 11.5415603f;  // 8*log2(e)

  for (int pass = 0; pass < 2; ++pass) {
    const int qtile = pass ? (63 - pair) : pair;
    const int qbase = qtile * 64;

    __syncthreads();
#pragma unroll
    for (int i = 0; i < 2; ++i) {  // Q: 8 chunks x 8 rows
      const int chunk = wave * 2 + i;
      const int r = chunk * 8 + rs;
      async_ld16(Q + (size_t)(qbase + r) * kD + h * kDh + ((cs ^ (r & 7)) << 3),
                 Qs + chunk * 512);
    }
    __syncthreads();

    half8 qf[2];
#pragma unroll
    for (int kt = 0; kt < 2; ++kt) {
      const int row = wave * 16 + lrow;
      qf[kt] = *reinterpret_cast<const half8*>(
          &Qs[row * 64 + (((kt * 4 + quad) ^ (row & 7)) << 3)]);
    }

    float lst[4] = {0.f, 0.f, 0.f, 0.f};
    floatx4 oacc[4] = {};
    const int qw = qbase + wave * 16;

    for (int t = split; t <= qtile; t += 2) {
      const int k0 = t * 64;
      __syncthreads();
#pragma unroll
      for (int i = 0; i < 4; ++i) {
        const int c2 = wave * 4 + i;
        if (c2 < 8) {
          const int r = c2 * 8 + rs;
          async_ld16(K + (size_t)(k0 + r) * kD + h * kDh + ((cs ^ (r & 7)) << 3),
                     Ks + c2 * 512);
        } else {
          const int c = c2 - 8;
          const int r = c * 8 + rs;
          async_ld16(Vt + (size_t)(h * kDh + r) * kS + k0 + ((cs ^ (r & 7)) << 3),
                     Vs + c * 512);
        }
      }
      __syncthreads();

      const bool diag = (t == qtile);

      floatx4 sacc[4] = {};
#pragma unroll
      for (int jt = 0; jt < 4; ++jt) {
        if (diag && jt > wave) continue;  // fully-masked key block
#pragma unroll
        for (int kt = 0; kt < 2; ++kt) {
          const int rb = jt * 16 + lrow;
          half8 bfk = *reinterpret_cast<const half8*>(
              &Ks[rb * 64 + (((kt * 4 + quad) ^ (rb & 7)) << 3)]);
          sacc[jt] = __builtin_amdgcn_mfma_f32_16x16x32_f16(qf[kt], bfk, sacc[jt], 0, 0, 0);
        }
      }

      if (diag) {
#pragma unroll
        for (int jt = 0; jt < 4; ++jt) {
          const int kg = k0 + jt * 16 + lrow;
#pragma unroll
          for (int r = 0; r < 4; ++r)
            if (kg > qw + quad * 4 + r) sacc[jt][r] = -1e30f;
        }
      }

#pragma unroll
      for (int jt = 0; jt < 4; ++jt)
#pragma unroll
        for (int r = 0; r < 4; ++r) {
          const float p = exp2f(sacc[jt][r] - kOff);
          sacc[jt][r] = p;
          lst[r] += p;
        }

#pragma unroll
      for (int jt = 0; jt < 4; ++jt)
#pragma unroll
        for (int r = 0; r < 4; ++r)
          Ps[(wave * 16 + quad * 4 + r) * 72 + jt * 16 + lrow] = (_Float16)sacc[jt][r];

      const int ktmax = (diag && wave < 2) ? 1 : 2;
      for (int kt = 0; kt < ktmax; ++kt) {
        half8 pf = *reinterpret_cast<const half8*>(
            &Ps[(wave * 16 + lrow) * 72 + (kt * 4 + quad) * 8]);
#pragma unroll
        for (int jt = 0; jt < 4; ++jt) {
          const int rb = jt * 16 + lrow;
          half8 vf = *reinterpret_cast<const half8*>(
              &Vs[rb * 64 + (((kt * 4 + quad) ^ (rb & 7)) << 3)]);
          oacc[jt] = __builtin_amdgcn_mfma_f32_16x16x32_f16(pf, vf, oacc[jt], 0, 0, 0);
        }
      }
    }

    // epilogue: reduce l over 16 cols, accumulate partials
#pragma unroll
    for (int r = 0; r < 4; ++r)
#pragma unroll
      for (int off = 8; off; off >>= 1) lst[r] += __shfl_xor(lst[r], off);
#pragma unroll
    for (int r = 0; r < 4; ++r) {
      const int qg = qw + quad * 4 + r;
      if (lrow == 0) atomicAdd(Lacc + qg * kH + h, lst[r]);
#pragma unroll
      for (int jt = 0; jt < 4; ++jt)
        atomicAdd(Oacc + ((size_t)qg * kH + h) * kDh + jt * 16 + lrow, oacc[jt][r]);
    }
  }
}

// ---------------------------------------------------------------- normalize: ho attn columns = Oacc / Lacc
__global__ __launch_bounds__(256) void norm_kernel(
    const float* __restrict__ Oacc, const float* __restrict__ Lacc,
    _Float16* __restrict__ ho) {
  const int idx = blockIdx.x * 256 + threadIdx.x;
  const int q = idx >> 10, rem = idx & 1023;
  const float l = Lacc[(q << 4) + (rem >> 6)];
  ho[(size_t)q * kKOut + kF + rem] = (_Float16)(Oacc[idx] / l);
}

// ---------------------------------------------------------------- launch
extern "C" void kernel_launch(void* const* d_in, const int* in_sizes, int n_in,
                              void* d_out, int out_size, void* d_ws, size_t ws_size,
                              hipStream_t stream) {
  const float* x        = (const float*)d_in[0];
  const float* ln_scale = (const float*)d_in[2];
  const float* ln_bias  = (const float*)d_in[3];
  const float* w_in     = (const float*)d_in[4];
  const float* b_in     = (const float*)d_in[5];
  const float* wq       = (const float*)d_in[6];
  const float* bq       = (const float*)d_in[7];
  const float* wk       = (const float*)d_in[8];
  const float* bk       = (const float*)d_in[9];
  const float* wv       = (const float*)d_in[10];
  const float* bv       = (const float*)d_in[11];
  const float* qn_scale = (const float*)d_in[12];
  const float* kn_scale = (const float*)d_in[13];
  const float* w_mo     = (const float*)d_in[14];
  const float* b_mo     = (const float*)d_in[15];
  const float* w_ao     = (const float*)d_in[16];
  const float* b_ao     = (const float*)d_in[17];
  float* out = (float*)d_out;

  char* ws = (char*)d_ws;
  size_t off = 0;
  auto alloc = [&](size_t bytes) { char* p = ws + off; off += bytes; return p; };
  // alias zone: xn+Wqkv dead after gemm_qkvin; Oacc/Lacc overlay
  char* zone = (char*)alloc((size_t)kS * kD * 2 + (size_t)kNQKV * kD * 2);
  _Float16* xn   = (_Float16*)zone;
  _Float16* Wqkv = (_Float16*)(zone + (size_t)kS * kD * 2);
  float* Oacc = (float*)zone;
  float* Lacc = (float*)(zone + (size_t)kS * kD * 4);
  _Float16* Wout = (_Float16*)alloc((size_t)kD * kKOut * 2);
  _Float16* ho   = (_Float16*)alloc((size_t)kS * kKOut * 2);
  _Float16* q_h  = (_Float16*)alloc((size_t)kS * kD * 2);
  _Float16* k_h  = (_Float16*)alloc((size_t)kS * kD * 2);
  _Float16* v_h  = (_Float16*)alloc((size_t)kS * kD * 2);
  _Float16* v_t  = (_Float16*)alloc((size_t)kS * kD * 2);

  prep0_kernel<<<12288 + 4096, 256, 0, stream>>>(
      w_in, wq, wk, wv, w_mo, w_ao, Wqkv, Wout, x, ln_scale, ln_bias, xn);

  gemm_qkvin<<<dim3(kS / 256, kNQKV / 256), 512, 0, stream>>>(
      xn, Wqkv, b_in, bq, bk, bv, qn_scale, kn_scale, ho, q_h, k_h, v_h);

  htrans_kernel<<<dim3(kD / 32, kS / 32), 256, 0, stream>>>(v_h, v_t, kS, kD);

  prep_kernel<<<(kS * kD + kS * kH + 255) / 256, 256, 0, stream>>>(
      x, b_mo, b_ao, out, Oacc, Lacc);

  fattn_kernel<<<dim3(32, kH, 2), 256, 0, stream>>>(q_h, k_h, v_t, Oacc, Lacc);

  norm_kernel<<<kS * kD / 256, 256, 0, stream>>>(Oacc, Lacc, ho);

  gemm_out<<<dim3(kS / 128, kD / 128, 2), 256, 0, stream>>>(ho, Wout, out);
}